// Round 7
// baseline (141.100 us; speedup 1.0000x reference)
//
#include <hip/hip_runtime.h>
#include <math.h>

#define SCALE 4.0f
#define H 128
#define E 64
#define TMAX 32

// d_ws layout (bytes):
//   [0      , 131072)  A-frag hi: short8 [w(8)][q(4)][kb(4)][lane(64)]
//   [131072 , 262144)  A-frag lo: same order
//   [262144 , 270336)  Uc: float4 {U0,U1,Cc,0} per gate row r (512 rows)
#define WS_LO_OFF  131072
#define WS_UC_OFF  262144

typedef __attribute__((ext_vector_type(8))) short short8;   // 8 bf16 = 4 VGPRs
typedef __attribute__((ext_vector_type(4))) float f32x4;

__device__ __forceinline__ bool is_nanf(float x) {
    return (__float_as_uint(x) & 0x7fffffffu) > 0x7f800000u;
}
__device__ __forceinline__ float rcpf(float x) { return __builtin_amdgcn_rcpf(x); }
__device__ __forceinline__ float sigm(float x) { return rcpf(1.0f + __expf(-x)); }
__device__ __forceinline__ float tanhfast(float x) {
    return fmaf(2.0f, rcpf(1.0f + __expf(-2.0f * x)), -1.0f);
}
// fp32 -> bf16 (RNE) and back.
__device__ __forceinline__ unsigned short bfhi(float f) {
    unsigned u = __float_as_uint(f);
    unsigned r = u + 0x7fffu + ((u >> 16) & 1u);
    return (unsigned short)(r >> 16);
}
__device__ __forceinline__ float bff(unsigned short h) {
    return __uint_as_float(((unsigned)h) << 16);
}

// ---------------- Pre-swizzle kernel ----------------
// Threads 0..8191: one per A-fragment slot (w,q,kb,lane): read 8 floats of
// W_hh (contiguous 32B), write bf16 hi/lo short8 to ws in fragment order.
// Threads 8192..8703: one per gate row r, folded input terms U0/U1/Cc.
__global__ __launch_bounds__(256)
void prep_kernel(const float* __restrict__ W_hh,
                 const float* __restrict__ W_ih,
                 const float* __restrict__ W_emb,
                 const float* __restrict__ b_emb,
                 const float* __restrict__ b_ih,
                 const float* __restrict__ b_hh,
                 char* __restrict__ ws)
{
    const int gid = blockIdx.x * 256 + threadIdx.x;
    if (gid < 8192) {
        const int lane = gid & 63;
        const int kb   = (gid >> 6) & 3;
        const int q    = (gid >> 8) & 3;
        const int w    = gid >> 10;
        const int mt   = q * 8 + w;
        const int row  = mt * 16 + (lane & 15);
        const int col0 = kb * 32 + (lane >> 4) * 8;
        const float* p = W_hh + (size_t)row * H + col0;
        short8 h8, l8;
        #pragma unroll
        for (int j = 0; j < 8; ++j) {
            const float f = p[j];
            const unsigned short hb = bfhi(f);
            h8[j] = (short)hb;
            l8[j] = (short)bfhi(f - bff(hb));
        }
        *(short8*)(ws + (size_t)gid * 16)             = h8;
        *(short8*)(ws + WS_LO_OFF + (size_t)gid * 16) = l8;
    } else if (gid < 8192 + 512) {
        const int r = gid - 8192;
        const float* wr = W_ih + (size_t)r * E;
        float s0 = 0.f, s1 = 0.f, sc = 0.f;
        #pragma unroll 8
        for (int k = 0; k < E; ++k) {
            const float wv = wr[k];
            s0 += wv * W_emb[2 * k + 0];
            s1 += wv * W_emb[2 * k + 1];
            sc += wv * b_emb[k];
        }
        f32x4 v = {s0, s1, sc + b_ih[r] + b_hh[r], 0.0f};
        *(f32x4*)(ws + WS_UC_OFF + (size_t)r * 16) = v;
    }
}

// ---------------- Main kernel ----------------
// MFMA persistent-LSTM, one barrier per step. R7 change: ONE scene per
// block (replicated across the 4 B-column groups) -> 512 blocks -> TWO
// blocks per CU. The per-step latency chain (barrier + ds_read latency +
// MFMA dep chain + epilogue) was the R5/R6 bottleneck with both pipes
// ~10% busy and half the CUs idle; two independent blocks per CU overlap
// their chains. LDS 22.5KB x2 fits; VGPR 128 -> 16 waves/CU (cap).
__global__ __launch_bounds__(512, 2)
void lstm_disc_kernel(
    const float* __restrict__ observed,
    const float* __restrict__ prediction,
    const int* __restrict__ batch_split,
    const char* __restrict__ ws,
    const float* __restrict__ W1, const float* __restrict__ b1,
    const float* __restrict__ W2, const float* __restrict__ b2,
    const float* __restrict__ W3, const float* __restrict__ b3,
    float* __restrict__ out,
    int N, int T_obs, int T_total, int n_scenes)
{
    // h as bf16 hi/lo, parity double-buffered, rows = q2 + 4*replica.
    __shared__ __align__(16) short hb_hi[2][4][16][8];
    __shared__ __align__(16) short hb_lo[2][4][16][8];
    __shared__ float h32[H];                 // final-step fp32 h for MLP
    __shared__ float px[TMAX], py[TMAX];
    __shared__ float aA[TMAX], bA[TMAX];
    __shared__ int   mA[TMAX];
    __shared__ float x1s[H / 2];
    __shared__ float x2s[H / 4];

    const int tid  = threadIdx.x;
    const int wave = tid >> 6;
    const int lane = tid & 63;
    const int ln15 = lane & 15;     // MFMA m / col field
    const int g4   = lane >> 4;     // MFMA quad field
    const int es   = ln15 & 3;      // replica index (single scene)
    const int ea   = ln15 >> 2;     // epilogue reg index
    const int eu   = wave * 16 + g4 * 4 + ea;   // epilogue hidden unit
    const int scene = blockIdx.x;

    // ---- Prologue ----
    // A-fragment streams first: 32 coalesced dwordx4 per thread, vmcnt
    // overlaps the rest of the prologue.
    short8 ahi[4][4], alo[4][4];
    #pragma unroll
    for (int q = 0; q < 4; ++q) {
        #pragma unroll
        for (int kb = 0; kb < 4; ++kb) {
            const size_t idx = ((size_t)((wave * 4 + q) * 4 + kb) * 64 + lane) * 16;
            ahi[q][kb] = *(const short8*)(ws + idx);
            alo[q][kb] = *(const short8*)(ws + WS_LO_OFF + idx);
        }
    }
    // Folded input terms for this lane's epilogue unit eu.
    float U0r[4], U1r[4], Ccr[4];
    #pragma unroll
    for (int q = 0; q < 4; ++q) {
        const f32x4 v = *(const f32x4*)(ws + WS_UC_OFF + (size_t)(eu + q * H) * 16);
        U0r[q] = v[0]; U1r[q] = v[1]; Ccr[q] = v[2];
    }

    if (tid < TMAX) {
        const int t = tid;
        const int agent = (scene < n_scenes) ? batch_split[scene] : 0;
        if (t < T_total) {
            const float* src = (t < T_obs)
                ? (observed   + (size_t)t           * N * 2)
                : (prediction + (size_t)(t - T_obs) * N * 2);
            px[t] = src[(size_t)agent * 2 + 0];
            py[t] = src[(size_t)agent * 2 + 1];
        }
    }
    {   // zero both parities of hb_hi / hb_lo (512 ints each array)
        int* zh = (int*)hb_hi;
        int* zl = (int*)hb_lo;
        if (tid < 512) { zh[tid] = 0; zl[tid] = 0; }
    }
    __syncthreads();

    if (tid < TMAX) {
        const int t = tid;
        if (t < T_total - 1) {
            const bool m = !(is_nanf(px[t]) || is_nanf(px[t + 1]));
            aA[t] = m ? SCALE * (px[t + 1] - px[t]) : 0.0f;
            bA[t] = m ? SCALE * (py[t + 1] - py[t]) : 0.0f;
            mA[t] = m ? 1 : 0;
        }
    }

    // h-writeback coordinates for unit eu, replica es: row = q2 + 4*es.
    const int wb_kb = eu >> 5;
    const int wb_ln = ((eu >> 3) & 3) + 4 * es;
    const int wb_j  = eu & 7;

    float c_st = 0.0f, h_st = 0.0f;
    __syncthreads();

    // ---- Recurrent loop: ONE barrier per step ----
    for (int t = 0; t < T_total - 1; ++t) {
        const int rp = t & 1, wp = rp ^ 1;

        const float aa = aA[t];
        const float bb = bA[t];
        const int   mm = mA[t];

        // B fragments: row g4 + 4*replica; broadcast within 4-lane groups,
        // 16 distinct b128 addrs at 2-way banks (free).
        short8 bhi[4], blo[4];
        #pragma unroll
        for (int kb = 0; kb < 4; ++kb) {
            bhi[kb] = *(const short8*)&hb_hi[rp][kb][g4 + 4 * es][0];
            blo[kb] = *(const short8*)&hb_lo[rp][kb][g4 + 4 * es][0];
        }

        f32x4 accA[4], accB[4];
        #pragma unroll
        for (int q = 0; q < 4; ++q) {
            accA[q] = (f32x4){0.f, 0.f, 0.f, 0.f};
            accB[q] = (f32x4){0.f, 0.f, 0.f, 0.f};
        }
        #pragma unroll
        for (int kb = 0; kb < 4; ++kb) {
            #pragma unroll
            for (int q = 0; q < 4; ++q)
                accA[q] = __builtin_amdgcn_mfma_f32_16x16x32_bf16(ahi[q][kb], bhi[kb], accA[q], 0, 0, 0);
        }
        #pragma unroll
        for (int kb = 0; kb < 4; ++kb) {
            #pragma unroll
            for (int q = 0; q < 4; ++q) {
                accA[q] = __builtin_amdgcn_mfma_f32_16x16x32_bf16(ahi[q][kb], blo[kb], accA[q], 0, 0, 0);
                accB[q] = __builtin_amdgcn_mfma_f32_16x16x32_bf16(alo[q][kb], bhi[kb], accB[q], 0, 0, 0);
            }
        }

        // In-lane epilogue: this lane's C element is reg 'ea' of each gate.
        const float p0 = accA[0][ea] + accB[0][ea] + Ccr[0] + aa * U0r[0] + bb * U1r[0];
        const float p1 = accA[1][ea] + accB[1][ea] + Ccr[1] + aa * U0r[1] + bb * U1r[1];
        const float p2 = accA[2][ea] + accB[2][ea] + Ccr[2] + aa * U0r[2] + bb * U1r[2];
        const float p3 = accA[3][ea] + accB[3][ea] + Ccr[3] + aa * U0r[3] + bb * U1r[3];
        const float ig = sigm(p0);
        const float fg = sigm(p1);
        const float gg = tanhfast(p2);
        const float og = sigm(p3);
        const float c2 = fg * c_st + ig * gg;
        const float h2 = og * tanhfast(c2);
        if (mm) { c_st = c2; h_st = h2; }

        const unsigned short hhi = bfhi(h_st);
        const unsigned short hlo = bfhi(h_st - bff(hhi));
        hb_hi[wp][wb_kb][wb_ln][wb_j] = (short)hhi;
        hb_lo[wp][wb_kb][wb_ln][wb_j] = (short)hlo;
        if (t == T_total - 2 && es == 0) h32[eu] = h_st;

        __syncthreads();
    }

    // ---- MLP head: 128 -> 64 -> 32 -> 1, relu (single scene) ----
    if (tid < H / 2) {
        const int u = tid;
        const float4* wr = (const float4*)(W1 + (size_t)u * H);
        const float4* hv = (const float4*)h32;
        float sum = b1[u];
        #pragma unroll
        for (int k = 0; k < H / 4; ++k) {
            const float4 w = wr[k], h = hv[k];
            sum += h.x * w.x + h.y * w.y + h.z * w.z + h.w * w.w;
        }
        x1s[u] = fmaxf(sum, 0.f);
    }
    __syncthreads();
    if (tid < H / 4) {
        const int u = tid;
        const float4* wr = (const float4*)(W2 + (size_t)u * (H / 2));
        const float4* xv = (const float4*)x1s;
        float sum = b2[u];
        #pragma unroll
        for (int k = 0; k < H / 8; ++k) {
            const float4 w = wr[k], x = xv[k];
            sum += x.x * w.x + x.y * w.y + x.z * w.z + x.w * w.w;
        }
        x2s[u] = fmaxf(sum, 0.f);
    }
    __syncthreads();
    if (tid == 0 && scene < n_scenes) {
        float sum = b3[0];
        #pragma unroll
        for (int k = 0; k < H / 4; ++k) sum += x2s[k] * W3[k];
        out[scene] = fmaxf(sum, 0.f);
    }
}

extern "C" void kernel_launch(void* const* d_in, const int* in_sizes, int n_in,
                              void* d_out, int out_size, void* d_ws, size_t ws_size,
                              hipStream_t stream) {
    const float* observed   = (const float*)d_in[0];
    const float* prediction = (const float*)d_in[1];
    // d_in[2] = goals (unused by the reference computation)
    const int*   batch_split = (const int*)d_in[3];
    const float* W_emb = (const float*)d_in[4];
    const float* b_emb = (const float*)d_in[5];
    const float* W_ih  = (const float*)d_in[6];
    const float* W_hh  = (const float*)d_in[7];
    const float* b_ih  = (const float*)d_in[8];
    const float* b_hh  = (const float*)d_in[9];
    const float* W1 = (const float*)d_in[10];
    const float* b1 = (const float*)d_in[11];
    const float* W2 = (const float*)d_in[12];
    const float* b2 = (const float*)d_in[13];
    const float* W3 = (const float*)d_in[14];
    const float* b3 = (const float*)d_in[15];
    float* out = (float*)d_out;

    const int N       = in_sizes[2] / 2;               // goals is (N,2)
    const int T_obs   = in_sizes[0] / (2 * N);         // observed (T_obs,N,2)
    const int T_total = T_obs + in_sizes[1] / (2 * N); // 21
    const int n_scenes = in_sizes[3] - 1;              // batch_split has n+1 entries

    prep_kernel<<<36, 256, 0, stream>>>(
        W_hh, W_ih, W_emb, b_emb, b_ih, b_hh, (char*)d_ws);

    lstm_disc_kernel<<<n_scenes, 512, 0, stream>>>(   // 1 scene/block, 2 blocks/CU
        observed, prediction, batch_split, (const char*)d_ws,
        W1, b1, W2, b2, W3, b3,
        out, N, T_obs, T_total, n_scenes);
}

// Round 8
// 111.758 us; speedup vs baseline: 1.2626x; 1.2626x over previous
//
#include <hip/hip_runtime.h>
#include <math.h>

#define SCALE 4.0f
#define H 128
#define E 64
#define NS 2            // scenes per block (each replicated 2x across B cols)
#define TMAX 32

// d_ws layout (bytes):
//   [0      , 131072)  A-frag f16: f16x8 [w(8)][q(4)][kb(4)][lane(64)]
//   [131072 , 139264)  Uc: float4 {U0,U1,Cc,0} per gate row r (512 rows)
#define WS_UC_OFF  131072

typedef _Float16 f16x8 __attribute__((ext_vector_type(8)));   // 4 VGPRs
typedef __attribute__((ext_vector_type(4))) float f32x4;

__device__ __forceinline__ bool is_nanf(float x) {
    return (__float_as_uint(x) & 0x7fffffffu) > 0x7f800000u;
}
__device__ __forceinline__ float rcpf(float x) { return __builtin_amdgcn_rcpf(x); }
__device__ __forceinline__ float sigm(float x) { return rcpf(1.0f + __expf(-x)); }
__device__ __forceinline__ float tanhfast(float x) {
    return fmaf(2.0f, rcpf(1.0f + __expf(-2.0f * x)), -1.0f);
}

// ---------------- Pre-swizzle kernel ----------------
// Threads 0..8191: one per A-fragment slot (w,q,kb,lane): read 8 floats of
// W_hh (contiguous 32B), write f16x8 to ws in fragment order.
// Threads 8192..8703: one per gate row r, folded input terms U0/U1/Cc.
__global__ __launch_bounds__(256)
void prep_kernel(const float* __restrict__ W_hh,
                 const float* __restrict__ W_ih,
                 const float* __restrict__ W_emb,
                 const float* __restrict__ b_emb,
                 const float* __restrict__ b_ih,
                 const float* __restrict__ b_hh,
                 char* __restrict__ ws)
{
    const int gid = blockIdx.x * 256 + threadIdx.x;
    if (gid < 8192) {
        const int lane = gid & 63;
        const int kb   = (gid >> 6) & 3;
        const int q    = (gid >> 8) & 3;
        const int w    = gid >> 10;
        const int mt   = q * 8 + w;
        const int row  = mt * 16 + (lane & 15);
        const int col0 = kb * 32 + (lane >> 4) * 8;
        const float* p = W_hh + (size_t)row * H + col0;
        f16x8 h8;
        #pragma unroll
        for (int j = 0; j < 8; ++j) h8[j] = (_Float16)p[j];
        *(f16x8*)(ws + (size_t)gid * 16) = h8;
    } else if (gid < 8192 + 512) {
        const int r = gid - 8192;
        const float* wr = W_ih + (size_t)r * E;
        float s0 = 0.f, s1 = 0.f, sc = 0.f;
        #pragma unroll 8
        for (int k = 0; k < E; ++k) {
            const float wv = wr[k];
            s0 += wv * W_emb[2 * k + 0];
            s1 += wv * W_emb[2 * k + 1];
            sc += wv * b_emb[k];
        }
        f32x4 v = {s0, s1, sc + b_ih[r] + b_hh[r], 0.0f};
        *(f32x4*)(ws + WS_UC_OFF + (size_t)r * 16) = v;
    }
}

// ---------------- Main kernel ----------------
// MFMA persistent-LSTM, one barrier per step. R8 changes vs R7:
//  - f16 2-term split (W single f16, h = f16 hi+lo): 32 MFMA/wave/step
//    (was 48), A-fragments 64 VGPRs (was 128 -> AGPR churn was inflating
//    VALUBusy in R7).
//  - NS=2 scenes x 2 replicas, 256 blocks: every CU busy at half R7's
//    per-CU MFMA work.
//  - 8 independent 4-deep MFMA chains for ILP.
__global__ __launch_bounds__(512, 2)
void lstm_disc_kernel(
    const float* __restrict__ observed,
    const float* __restrict__ prediction,
    const int* __restrict__ batch_split,
    const char* __restrict__ ws,
    const float* __restrict__ W1, const float* __restrict__ b1,
    const float* __restrict__ W2, const float* __restrict__ b2,
    const float* __restrict__ W3, const float* __restrict__ b3,
    float* __restrict__ out,
    int N, int T_obs, int T_total, int n_scenes)
{
    // h as f16 hi/lo, parity double-buffered, row = q2 + 4*scene (8 rows).
    __shared__ __align__(16) _Float16 hb_hi[2][4][8][8];
    __shared__ __align__(16) _Float16 hb_lo[2][4][8][8];
    __shared__ float h32[NS][H];             // final-step fp32 h for MLP
    __shared__ float px[NS][TMAX], py[NS][TMAX];
    __shared__ float aA[NS][TMAX], bA[NS][TMAX];
    __shared__ int   mA[NS][TMAX];
    __shared__ float x1s[NS][H / 2];
    __shared__ float x2s[NS][H / 4];

    const int tid  = threadIdx.x;
    const int wave = tid >> 6;
    const int lane = tid & 63;
    const int ln15 = lane & 15;     // MFMA m / col field
    const int g4   = lane >> 4;     // MFMA quad field
    const int es   = ln15 & 3;      // slot 0..3; scene = es & 1
    const int esc  = es & 1;        // scene within block
    const int ea   = ln15 >> 2;     // epilogue reg index
    const int eu   = wave * 16 + g4 * 4 + ea;   // epilogue hidden unit
    const int sc0  = blockIdx.x * NS;

    // ---- Prologue ----
    // A-fragment streams first (16 coalesced dwordx4/thread).
    f16x8 ahi[4][4];
    #pragma unroll
    for (int q = 0; q < 4; ++q) {
        #pragma unroll
        for (int kb = 0; kb < 4; ++kb) {
            const size_t idx = ((size_t)((wave * 4 + q) * 4 + kb) * 64 + lane) * 16;
            ahi[q][kb] = *(const f16x8*)(ws + idx);
        }
    }
    // Folded input terms for this lane's epilogue unit eu.
    float U0r[4], U1r[4], Ccr[4];
    #pragma unroll
    for (int q = 0; q < 4; ++q) {
        const f32x4 v = *(const f32x4*)(ws + WS_UC_OFF + (size_t)(eu + q * H) * 16);
        U0r[q] = v[0]; U1r[q] = v[1]; Ccr[q] = v[2];
    }

    if (tid < NS * TMAX) {
        const int s = tid >> 5, t = tid & 31;
        const int scene = sc0 + s;
        const int agent = (scene < n_scenes) ? batch_split[scene] : 0;
        if (t < T_total) {
            const float* src = (t < T_obs)
                ? (observed   + (size_t)t           * N * 2)
                : (prediction + (size_t)(t - T_obs) * N * 2);
            px[s][t] = src[(size_t)agent * 2 + 0];
            py[s][t] = src[(size_t)agent * 2 + 1];
        }
    }
    {   // zero both parities of hb_hi / hb_lo (256 ints each array)
        int* zh = (int*)hb_hi;
        int* zl = (int*)hb_lo;
        if (tid < 256) { zh[tid] = 0; zl[tid] = 0; }
    }
    __syncthreads();

    if (tid < NS * TMAX) {
        const int s = tid >> 5, t = tid & 31;
        if (t < T_total - 1) {
            const bool m = !(is_nanf(px[s][t]) || is_nanf(px[s][t + 1]));
            aA[s][t] = m ? SCALE * (px[s][t + 1] - px[s][t]) : 0.0f;
            bA[s][t] = m ? SCALE * (py[s][t + 1] - py[s][t]) : 0.0f;
            mA[s][t] = m ? 1 : 0;
        }
    }

    // h-writeback coordinates for unit eu, scene esc: row = q2 + 4*esc.
    const int wb_kb = eu >> 5;
    const int wb_ln = ((eu >> 3) & 3) + 4 * esc;
    const int wb_j  = eu & 7;
    const bool wb_on = (es < 2);    // slots 2,3 are replicas: don't write

    float c_st = 0.0f, h_st = 0.0f;
    __syncthreads();

    // ---- Recurrent loop: ONE barrier per step ----
    for (int t = 0; t < T_total - 1; ++t) {
        const int rp = t & 1, wp = rp ^ 1;

        const float aa = aA[esc][t];
        const float bb = bA[esc][t];
        const int   mm = mA[esc][t];

        // B fragments: row g4 + 4*scene; 8 distinct b128 addrs (one per
        // bank group), broadcast to 8 lanes each -> conflict-free.
        f16x8 bhi[4], blo[4];
        #pragma unroll
        for (int kb = 0; kb < 4; ++kb) {
            bhi[kb] = *(const f16x8*)&hb_hi[rp][kb][g4 + 4 * esc][0];
            blo[kb] = *(const f16x8*)&hb_lo[rp][kb][g4 + 4 * esc][0];
        }

        // 8 independent 4-deep chains.
        f32x4 accH[4], accL[4];
        #pragma unroll
        for (int q = 0; q < 4; ++q) {
            accH[q] = (f32x4){0.f, 0.f, 0.f, 0.f};
            accL[q] = (f32x4){0.f, 0.f, 0.f, 0.f};
        }
        #pragma unroll
        for (int kb = 0; kb < 4; ++kb) {
            #pragma unroll
            for (int q = 0; q < 4; ++q) {
                accH[q] = __builtin_amdgcn_mfma_f32_16x16x32_f16(ahi[q][kb], bhi[kb], accH[q], 0, 0, 0);
                accL[q] = __builtin_amdgcn_mfma_f32_16x16x32_f16(ahi[q][kb], blo[kb], accL[q], 0, 0, 0);
            }
        }

        // In-lane epilogue: this lane's C element is reg 'ea' of each gate.
        const float p0 = accH[0][ea] + accL[0][ea] + Ccr[0] + aa * U0r[0] + bb * U1r[0];
        const float p1 = accH[1][ea] + accL[1][ea] + Ccr[1] + aa * U0r[1] + bb * U1r[1];
        const float p2 = accH[2][ea] + accL[2][ea] + Ccr[2] + aa * U0r[2] + bb * U1r[2];
        const float p3 = accH[3][ea] + accL[3][ea] + Ccr[3] + aa * U0r[3] + bb * U1r[3];
        const float ig = sigm(p0);
        const float fg = sigm(p1);
        const float gg = tanhfast(p2);
        const float og = sigm(p3);
        const float c2 = fg * c_st + ig * gg;
        const float h2 = og * tanhfast(c2);
        if (mm) { c_st = c2; h_st = h2; }

        if (wb_on) {
            const _Float16 hhi = (_Float16)h_st;
            const _Float16 hlo = (_Float16)(h_st - (float)hhi);
            hb_hi[wp][wb_kb][wb_ln][wb_j] = hhi;
            hb_lo[wp][wb_kb][wb_ln][wb_j] = hlo;
            if (t == T_total - 2) h32[esc][eu] = h_st;
        }
        __syncthreads();
    }

    // ---- MLP head: 128 -> 64 -> 32 -> 1, relu (NS=2 scenes) ----
    if (tid < NS * (H / 2)) {
        const int s = tid >> 6, u = tid & 63;
        const float4* wr = (const float4*)(W1 + (size_t)u * H);
        const float4* hv = (const float4*)h32[s];
        float sum = b1[u];
        #pragma unroll
        for (int k = 0; k < H / 4; ++k) {
            const float4 w = wr[k], h = hv[k];
            sum += h.x * w.x + h.y * w.y + h.z * w.z + h.w * w.w;
        }
        x1s[s][u] = fmaxf(sum, 0.f);
    }
    __syncthreads();
    if (tid < NS * (H / 4)) {
        const int s = tid >> 5, u = tid & 31;
        const float4* wr = (const float4*)(W2 + (size_t)u * (H / 2));
        const float4* xv = (const float4*)x1s[s];
        float sum = b2[u];
        #pragma unroll
        for (int k = 0; k < H / 8; ++k) {
            const float4 w = wr[k], x = xv[k];
            sum += x.x * w.x + x.y * w.y + x.z * w.z + x.w * w.w;
        }
        x2s[s][u] = fmaxf(sum, 0.f);
    }
    __syncthreads();
    if (tid < NS) {
        const int scene = sc0 + tid;
        if (scene < n_scenes) {
            float sum = b3[0];
            #pragma unroll
            for (int k = 0; k < H / 4; ++k) sum += x2s[tid][k] * W3[k];
            out[scene] = fmaxf(sum, 0.f);
        }
    }
}

extern "C" void kernel_launch(void* const* d_in, const int* in_sizes, int n_in,
                              void* d_out, int out_size, void* d_ws, size_t ws_size,
                              hipStream_t stream) {
    const float* observed   = (const float*)d_in[0];
    const float* prediction = (const float*)d_in[1];
    // d_in[2] = goals (unused by the reference computation)
    const int*   batch_split = (const int*)d_in[3];
    const float* W_emb = (const float*)d_in[4];
    const float* b_emb = (const float*)d_in[5];
    const float* W_ih  = (const float*)d_in[6];
    const float* W_hh  = (const float*)d_in[7];
    const float* b_ih  = (const float*)d_in[8];
    const float* b_hh  = (const float*)d_in[9];
    const float* W1 = (const float*)d_in[10];
    const float* b1 = (const float*)d_in[11];
    const float* W2 = (const float*)d_in[12];
    const float* b2 = (const float*)d_in[13];
    const float* W3 = (const float*)d_in[14];
    const float* b3 = (const float*)d_in[15];
    float* out = (float*)d_out;

    const int N       = in_sizes[2] / 2;               // goals is (N,2)
    const int T_obs   = in_sizes[0] / (2 * N);         // observed (T_obs,N,2)
    const int T_total = T_obs + in_sizes[1] / (2 * N); // 21
    const int n_scenes = in_sizes[3] - 1;              // batch_split has n+1 entries

    prep_kernel<<<34, 256, 0, stream>>>(
        W_hh, W_ih, W_emb, b_emb, b_ih, b_hh, (char*)d_ws);

    const int nblocks = (n_scenes + NS - 1) / NS;      // 2 scenes/block -> 256 blocks
    lstm_disc_kernel<<<nblocks, 512, 0, stream>>>(
        observed, prediction, batch_split, (const char*)d_ws,
        W1, b1, W2, b2, W3, b3,
        out, N, T_obs, T_total, n_scenes);
}